// Round 8
// baseline (150.412 us; speedup 1.0000x reference)
//
#include <hip/hip_runtime.h>
#include <stdint.h>

typedef unsigned short u16;
typedef unsigned int u32;
typedef unsigned long long u64;
typedef unsigned char u8;

typedef __attribute__((ext_vector_type(4))) int   i32x4;
typedef __attribute__((ext_vector_type(8))) int   i32x8;
typedef __attribute__((ext_vector_type(4))) float f32x4;
typedef __attribute__((ext_vector_type(2))) float f32x2;

// ---------------- workspace layout (bytes) ----------------
#define OFF_WQ4  0u                                  // fp4 e2m1 W, fragment order:
// 16B slot = ks*2048 + (j*4 + kblock), ks = k>>7, kblock = (k>>5)&3,
// elem i = k&31 -> byte i>>1, even i = lo nibble (matches A spread order)
#define WQ4_BYTES (2u * 32768u)                      // 64 KiB
#define OFF_SCL  (OFF_WQ4 + WQ4_BYTES)               // float[256]: colmax/12

// ---- packed f32 fma with per-source op_sel broadcasts (zero-mov taps) ----
__device__ __forceinline__ f32x2 pk_fma(f32x2 a, f32x2 b, f32x2 c) {
    f32x2 d;
    asm("v_pk_fma_f32 %0, %1, %2, %3"
        : "=v"(d) : "v"(a), "v"(b), "v"(c));
    return d;
}
// d = a.lo * b + a.hi
__device__ __forceinline__ f32x2 pk_fma_lw(f32x2 a, f32x2 b) {
    f32x2 d;
    asm("v_pk_fma_f32 %0, %1, %2, %1 op_sel:[0,0,1] op_sel_hi:[0,1,1]"
        : "=v"(d) : "v"(a), "v"(b));
    return d;
}
// d = a.hi * b + c
__device__ __forceinline__ f32x2 pk_fma_b11(f32x2 a, f32x2 b, f32x2 c) {
    f32x2 d;
    asm("v_pk_fma_f32 %0, %1, %2, %3 op_sel:[1,0,0] op_sel_hi:[1,1,1]"
        : "=v"(d) : "v"(a), "v"(b), "v"(c));
    return d;
}
// d = a.lo * b + c
__device__ __forceinline__ f32x2 pk_fma_b00(f32x2 a, f32x2 b, f32x2 c) {
    f32x2 d;
    asm("v_pk_fma_f32 %0, %1, %2, %3 op_sel:[0,0,0] op_sel_hi:[0,1,1]"
        : "=v"(d) : "v"(a), "v"(b), "v"(c));
    return d;
}

// ---- 8 bits -> 8 e2m1 nibbles (0x0 / 0x2) via v_perm 2-bit->byte LUT ----
__device__ __forceinline__ u32 nib_perm(u32 byte) {
    u32 t1 = byte | (byte << 6);
    u32 t2 = t1 | (t1 << 12);
    u32 sel = t2 & 0x03030303u;
    // LUT bytes: idx0->0x00 idx1->0x02 idx2->0x20 idx3->0x22
    return __builtin_amdgcn_perm(0x22200200u, 0x22200200u, sel);
}

// ---------------- kernel 1: W prep (256 blocks) ----------------
__global__ __launch_bounds__(256) void prep_kernel(
    const float* __restrict__ lin_w, uint8_t* __restrict__ ws) {
    __shared__ float red[256];
    __shared__ u8 nib[256];
    int j = blockIdx.x, k = threadIdx.x;
    float wv = lin_w[j * 256 + k];
    red[k] = fabsf(wv);
    __syncthreads();
    #pragma unroll
    for (int s = 128; s > 0; s >>= 1) {
        if (k < s) red[k] = fmaxf(red[k], red[k + s]);
        __syncthreads();
    }
    float m = red[0];
    float S = (m > 0.f) ? 6.0f / m : 0.f;
    float v6 = wv * S;
    float av = fabsf(v6);
    int code;
    if      (av < 0.25f) code = 0;
    else if (av < 0.75f) code = 1;
    else if (av < 1.25f) code = 2;
    else if (av < 1.75f) code = 3;
    else if (av < 2.5f)  code = 4;
    else if (av < 3.5f)  code = 5;
    else if (av < 5.0f)  code = 6;
    else                 code = 7;
    nib[k] = (u8)(((v6 < 0.f && code) ? 8 : 0) | code);
    __syncthreads();
    if (k < 128) {
        u8 byte = (u8)(nib[2 * k] | (nib[2 * k + 1] << 4));
        int ks = k >> 6, kb = (k >> 4) & 3, bi = k & 15;
        (ws + OFF_WQ4)[ks * 32768 + (j * 4 + kb) * 16 + bi] = byte;
    }
    if (k == 0) ((float*)(ws + OFF_SCL))[j] = m * (1.0f / 12.0f);
}

// ---------------- kernel 2: FUSED encoder + GEMM + scan ----------------
// 1024 blocks x 256 threads = 4 blocks/CU EXACT full residency (16 waves/
// CU, 2x R6's TLP on a latency-bound kernel). Block = (b0, c), handles the
// 2 sequences n = b0*32+c and n+1024 (the b-halves).
//   1. encoder: tid<128 run R6's verified packed-f32x2 chain (pair = the
//      two b-halves); bits -> LDS u32[2 seq][8 hc][128 l] (8 KB).
//   2. one barrier.
//   3. per seq s=0..1: R6-verbatim register-resident GEMM K-loop
//      (nib_perm spread under MFMA pipe, zero LDS / zero barriers) +
//      wave-private 4-phase epilogue, stride-32 XOR-swizzled
//      (col ^= (row&7)<<2 on write AND read: bank-clean b128 both sides)
//      + u-scan + coalesced out store.
// LDS = 8192 bits + 4 waves x 8192 ZW = 40960 (cfl overlays ZW region).
__global__ __launch_bounds__(256, 4) void enc_gemm_kernel(
    const float* __restrict__ x,
    const float* __restrict__ conv_w, const float* __restrict__ conv_b,
    const float* __restrict__ gamma,  const float* __restrict__ beta,
    const float* __restrict__ mean,   const float* __restrict__ var,
    const uint4* __restrict__ wq4,
    const float* __restrict__ lin_b,  const float* __restrict__ sclp,
    float* __restrict__ out) {
    __shared__ __align__(16) uint8_t smem[40960];
    u32*   bits = (u32*)smem;                        // [2][8][128]
    f32x4* cfl  = (f32x4*)(smem + 8192);             // overlay on ZW region

    int tid  = threadIdx.x;
    int blk  = blockIdx.x;                           // 0..1023
    int lane = tid & 63;
    int w    = tid >> 6;
    int l15  = lane & 15;
    int quad = lane >> 4;
    int lb   = w * 256 + l15 * 4 + quad;             // per-lane W slot base
    int b0   = blk >> 5;                             // 0..31
    int c    = blk & 31;

    // ---- scan constants (j = tid) ----
    float bias = lin_b[tid];
    float zscg = fmaxf(sclp[tid], 1e-37f);           // colmax/12, guarded
    float uth  = (1.0f - bias) / zscg;               // spike: u >= uth
    float urst = (0.0f - bias) / zscg;               // reset (v=0)

    // B: load BOTH ks halves upfront (8 x dwordx4, L2-resident); issued
    // early so latency hides under the encoder phase.
    i32x4 bb[2][4];
    #pragma unroll
    for (int ks = 0; ks < 2; ++ks)
        #pragma unroll
        for (int nf = 0; nf < 4; ++nf)
            bb[ks][nf] = ((const i32x4*)wq4)[(size_t)(ks * 2048 + nf * 64 + lb)];

    // ---- BN fold (coeffs pre-halved: folds tau=2) ----
    {
        int h = tid;
        float inv = gamma[h] / sqrtf(var[h] + 1e-5f);
        float K = (conv_b[h] - mean[h]) * inv + beta[h];
        f32x4 cc = {conv_w[h * 3 + 0] * inv * 0.5f,
                    conv_w[h * 3 + 1] * inv * 0.5f,
                    conv_w[h * 3 + 2] * inv * 0.5f, K * 0.5f};
        cfl[h] = cc;
    }
    __syncthreads();                                 // cfl visible

    // ---- encoder: tid<128, packed pair = (b-half 0, b-half 1) ----
    if (tid < 128) {
        int l  = tid;
        int xb = b0 * 4096 + l * 32 + c;
        float xb0 = x[xb],            xb1 = x[xb + 131072];
        float xa0 = (l > 0)   ? x[xb - 32]          : 0.f;
        float xa1 = (l > 0)   ? x[xb + 131072 - 32] : 0.f;
        float xc0 = (l < 127) ? x[xb + 32]          : 0.f;
        float xc1 = (l < 127) ? x[xb + 131072 + 32] : 0.f;
        u32* d0 = bits + l;                          // seq 0
        u32* d1 = d0 + 1024;                         // seq 1 (b-half 1)

        f32x2 XA = {xa0, xa1};
        f32x2 XB = {xb0, xb1};
        f32x2 XC = {xc0, xc1};
        const f32x2 hf2 = {0.5f, 0.5f};

        f32x2 v2 = {0.f, 0.f};
        #pragma unroll 1
        for (int hc = 0; hc < 8; ++hc) {
            u32 c0 = 0, c1 = 0;
            #pragma unroll
            for (int k = 0; k < 32; ++k) {
                f32x4 a4 = cfl[hc * 32 + k];
                f32x2 p0 = __builtin_shufflevector(a4, a4, 0, 1); // (w0,w1)
                f32x2 p1 = __builtin_shufflevector(a4, a4, 2, 3); // (w2,K)
                f32x2 e = pk_fma_lw(p1, XC);      // w2*xc + K
                e = pk_fma_b11(p0, XB, e);        // + w1*xb
                e = pk_fma_b00(p0, XA, e);        // + w0*xa
                v2 = pk_fma(hf2, v2, e);          // v = v/2 + e (pre-halved)
                bool s0 = (v2.x >= 1.0f);
                bool s1 = (v2.y >= 1.0f);
                c0 = (c0 << 1) | (u32)s0;
                c1 = (c1 << 1) | (u32)s1;
                v2.x = s0 ? 0.f : v2.x;
                v2.y = s1 ? 0.f : v2.y;
            }
            d0[hc * 128] = __builtin_bitreverse32(c0);  // bit i = spike(hc*32+i)
            d1[hc * 128] = __builtin_bitreverse32(c1);
        }
    }
    __syncthreads();                                 // bits ready, cfl dead

    // ---- GEMM + scan, 2 sequences ----
    float* ZW = (float*)(smem + 8192 + (size_t)w * 8192);   // [64 j][32] swz
    const u32* bp = bits + quad * 128 + l15;
    int wswz = (l15 & 7) << 2;                       // write swizzle key
    int rswz = (lane & 7) << 2;                      // read swizzle key

    #pragma unroll 1
    for (int s = 0; s < 2; ++s) {
        // A words (chunk hc = ks*4+quad, row l = mf*16+l15)
        u32 aw[8][2];
        #pragma unroll
        for (int mf = 0; mf < 8; ++mf)
            #pragma unroll
            for (int ks = 0; ks < 2; ++ks)
                aw[mf][ks] = bp[s * 1024 + ks * 512 + mf * 16];

        f32x4 acc[8][4];
        #pragma unroll
        for (int mf = 0; mf < 8; ++mf)
            #pragma unroll
            for (int nf = 0; nf < 4; ++nf) {
                f32x4 z = {0.f, 0.f, 0.f, 0.f};
                acc[mf][nf] = z;
            }

        // A fragment: upper half zeroed ONCE (fp4 FMT reads regs 0..3)
        i32x8 afr;
        afr[4] = 0; afr[5] = 0; afr[6] = 0; afr[7] = 0;

        #pragma unroll
        for (int ks = 0; ks < 2; ++ks) {
            i32x8 bfr[4];
            #pragma unroll
            for (int nf = 0; nf < 4; ++nf) {
                bfr[nf][0] = bb[ks][nf][0]; bfr[nf][1] = bb[ks][nf][1];
                bfr[nf][2] = bb[ks][nf][2]; bfr[nf][3] = bb[ks][nf][3];
                bfr[nf][4] = 0; bfr[nf][5] = 0; bfr[nf][6] = 0; bfr[nf][7] = 0;
            }
            #pragma unroll
            for (int mf = 0; mf < 8; ++mf) {
                u32 wb = aw[mf][ks];
                afr[0] = (int)nib_perm(wb & 0xFFu);
                afr[1] = (int)nib_perm((wb >> 8) & 0xFFu);
                afr[2] = (int)nib_perm((wb >> 16) & 0xFFu);
                afr[3] = (int)nib_perm(wb >> 24);
                #pragma unroll
                for (int nf = 0; nf < 4; ++nf) {
                    acc[mf][nf] =
                        __builtin_amdgcn_mfma_scale_f32_16x16x128_f8f6f4(
                            afr, bfr[nf], acc[mf][nf], 4, 4,  // fp4 x fp4
                            0, 0x7F7F7F7F, 0, 0x7F7F7F7F);    // scales 1.0
                }
            }
        }

        // ---- wave-private 4-phase epilogue, stride-32 XOR-swizzle ----
        // write col = (mm*16+quad*4) ^ ((row&7)<<2), row = nf*16+l15;
        // read  col = (g*4) ^ ((lane&7)<<2) at row = lane. Same XOR both
        // sides -> logical mapping unchanged; banks spread per 8-lane phase.
        float u = urst, sOut = 0.f;
        #pragma unroll
        for (int ph = 0; ph < 4; ++ph) {
            #pragma unroll
            for (int mm = 0; mm < 2; ++mm) {         // mf = ph*2+mm
                int mf = ph * 2 + mm;
                int col = ((mm << 4) | (quad << 2)) ^ wswz;
                #pragma unroll
                for (int nf = 0; nf < 4; ++nf)
                    *(f32x4*)(ZW + (nf * 16 + l15) * 32 + col) = acc[mf][nf];
            }
            #pragma unroll
            for (int g = 0; g < 8; ++g) {
                f32x4 z4 = *(const f32x4*)(ZW + lane * 32 + ((g << 2) ^ rswz));
                #pragma unroll
                for (int r = 0; r < 4; ++r) {
                    u = fmaf(0.5f, u, z4[r]);
                    bool sp = (u >= uth);
                    if (ph == 3 && g == 7 && r == 3) sOut = sp ? 1.f : 0.f;
                    u = sp ? urst : u;
                }
            }
        }
        int n = b0 * 32 + c + s * 1024;
        out[(size_t)n * 256 + tid]           = sOut; // (64,1,8192) flat
        out[524288u + (size_t)n * 256 + tid] = sOut; // (64,8192) flat
    }
}

// ---------------- launcher ----------------
extern "C" void kernel_launch(void* const* d_in, const int* in_sizes, int n_in,
                              void* d_out, int out_size, void* d_ws, size_t ws_size,
                              hipStream_t stream) {
    const float* x      = (const float*)d_in[0];
    const float* conv_w = (const float*)d_in[1];
    const float* conv_b = (const float*)d_in[2];
    const float* gamma  = (const float*)d_in[3];
    const float* beta   = (const float*)d_in[4];
    const float* mean   = (const float*)d_in[5];
    const float* var    = (const float*)d_in[6];
    const float* lin_w  = (const float*)d_in[7];
    const float* lin_b  = (const float*)d_in[8];
    uint8_t* ws = (uint8_t*)d_ws;
    float* out = (float*)d_out;

    hipLaunchKernelGGL(prep_kernel, dim3(256), dim3(256), 0, stream,
                       lin_w, ws);
    hipLaunchKernelGGL(enc_gemm_kernel, dim3(1024), dim3(256), 0, stream,
                       x, conv_w, conv_b, gamma, beta, mean, var,
                       (const uint4*)(ws + OFF_WQ4), lin_b,
                       (const float*)(ws + OFF_SCL), out);
}

// Round 9
// 108.021 us; speedup vs baseline: 1.3924x; 1.3924x over previous
//
#include <hip/hip_runtime.h>
#include <stdint.h>

typedef unsigned short u16;
typedef unsigned int u32;
typedef unsigned long long u64;
typedef unsigned char u8;

typedef __attribute__((ext_vector_type(4))) int   i32x4;
typedef __attribute__((ext_vector_type(8))) int   i32x8;
typedef __attribute__((ext_vector_type(4))) float f32x4;
typedef __attribute__((ext_vector_type(2))) float f32x2;

// ---------------- workspace layout (bytes) ----------------
#define OFF_WQ4  0u                                  // fp4 e2m1 W, fragment order:
// 16B slot = ks*2048 + (j*4 + kblock), ks = k>>7, kblock = (k>>5)&3,
// elem i = k&31 -> byte i>>1, even i = lo nibble (matches A spread order)
#define WQ4_BYTES (2u * 32768u)                      // 64 KiB
#define OFF_SCL  (OFF_WQ4 + WQ4_BYTES)               // float[256]: colmax/12

// ---- packed f32 fma with per-source op_sel broadcasts (zero-mov taps) ----
__device__ __forceinline__ f32x2 pk_fma(f32x2 a, f32x2 b, f32x2 c) {
    f32x2 d;
    asm("v_pk_fma_f32 %0, %1, %2, %3"
        : "=v"(d) : "v"(a), "v"(b), "v"(c));
    return d;
}
// d = a.lo * b + a.hi
__device__ __forceinline__ f32x2 pk_fma_lw(f32x2 a, f32x2 b) {
    f32x2 d;
    asm("v_pk_fma_f32 %0, %1, %2, %1 op_sel:[0,0,1] op_sel_hi:[0,1,1]"
        : "=v"(d) : "v"(a), "v"(b));
    return d;
}
// d = a.hi * b + c
__device__ __forceinline__ f32x2 pk_fma_b11(f32x2 a, f32x2 b, f32x2 c) {
    f32x2 d;
    asm("v_pk_fma_f32 %0, %1, %2, %3 op_sel:[1,0,0] op_sel_hi:[1,1,1]"
        : "=v"(d) : "v"(a), "v"(b), "v"(c));
    return d;
}
// d = a.lo * b + c
__device__ __forceinline__ f32x2 pk_fma_b00(f32x2 a, f32x2 b, f32x2 c) {
    f32x2 d;
    asm("v_pk_fma_f32 %0, %1, %2, %3 op_sel:[0,0,0] op_sel_hi:[0,1,1]"
        : "=v"(d) : "v"(a), "v"(b), "v"(c));
    return d;
}

// ---- 8 bits -> 8 e2m1 nibbles (0x0 / 0x2) via v_perm 2-bit->byte LUT ----
__device__ __forceinline__ u32 nib_perm(u32 byte) {
    u32 t1 = byte | (byte << 6);
    u32 t2 = t1 | (t1 << 12);
    u32 sel = t2 & 0x03030303u;
    // LUT bytes: idx0->0x00 idx1->0x02 idx2->0x20 idx3->0x22
    return __builtin_amdgcn_perm(0x22200200u, 0x22200200u, sel);
}

// ---------------- kernel 1: W prep (256 blocks) ----------------
__global__ __launch_bounds__(256) void prep_kernel(
    const float* __restrict__ lin_w, uint8_t* __restrict__ ws) {
    __shared__ float red[256];
    __shared__ u8 nib[256];
    int j = blockIdx.x, k = threadIdx.x;
    float wv = lin_w[j * 256 + k];
    red[k] = fabsf(wv);
    __syncthreads();
    #pragma unroll
    for (int s = 128; s > 0; s >>= 1) {
        if (k < s) red[k] = fmaxf(red[k], red[k + s]);
        __syncthreads();
    }
    float m = red[0];
    float S = (m > 0.f) ? 6.0f / m : 0.f;
    float v6 = wv * S;
    float av = fabsf(v6);
    int code;
    if      (av < 0.25f) code = 0;
    else if (av < 0.75f) code = 1;
    else if (av < 1.25f) code = 2;
    else if (av < 1.75f) code = 3;
    else if (av < 2.5f)  code = 4;
    else if (av < 3.5f)  code = 5;
    else if (av < 5.0f)  code = 6;
    else                 code = 7;
    nib[k] = (u8)(((v6 < 0.f && code) ? 8 : 0) | code);
    __syncthreads();
    if (k < 128) {
        u8 byte = (u8)(nib[2 * k] | (nib[2 * k + 1] << 4));
        int ks = k >> 6, kb = (k >> 4) & 3, bi = k & 15;
        (ws + OFF_WQ4)[ks * 32768 + (j * 4 + kb) * 16 + bi] = byte;
    }
    if (k == 0) ((float*)(ws + OFF_SCL))[j] = m * (1.0f / 12.0f);
}

// ---------------- kernel 2: FUSED encoder + phase-fused GEMM + scan ----
// 1024 blocks x 256 threads, __launch_bounds__(256,3) -> 3 blocks/CU,
// 12 waves/CU (1.5x R6 TLP). Block = (b0,c), 2 sequences (b-halves).
// KEY CHANGE vs R6/R8: the K-loop is fused into the epilogue phases.
// Per phase mf (8 phases): for each of the 2 seqs, compute ONLY that
// mf-row's acc (acc[4] = 16 regs live, not 128), write to wave-private
// ZW, then scan 16 t for BOTH seqs (two independent 12-cyc chains fill
// each other's bubbles). Total MFMA/spread/scan work identical to R6 --
// only register LIVENESS shrinks (R8 lesson: shrink live set, don't cap).
// aw read from bits LDS per phase (2 ds_read_b32) instead of a 32-reg
// preload. bfr[2][4] (64 regs) resident once -- fixes R7's B re-fetch.
// ZW: per wave 8 KB = 2 seq x [64 j][16 t]; slot swizzle ^= (row>>1)&3
// gives bandwidth-floor b128 on BOTH write (8 lanes / 4-bank group) and
// read (lane&7 spreads all 8 groups). LDS = 8192 bits + 32768 ZW = 40960.
__global__ __launch_bounds__(256, 3) void enc_gemm_kernel(
    const float* __restrict__ x,
    const float* __restrict__ conv_w, const float* __restrict__ conv_b,
    const float* __restrict__ gamma,  const float* __restrict__ beta,
    const float* __restrict__ mean,   const float* __restrict__ var,
    const uint4* __restrict__ wq4,
    const float* __restrict__ lin_b,  const float* __restrict__ sclp,
    float* __restrict__ out) {
    __shared__ __align__(16) uint8_t smem[40960];
    u32*   bits = (u32*)smem;                        // [2 bh][8 hc][128 l]
    f32x4* cfl  = (f32x4*)(smem + 8192);             // overlay on ZW region

    int tid  = threadIdx.x;
    int blk  = blockIdx.x;                           // 0..1023
    int lane = tid & 63;
    int w    = tid >> 6;
    int l15  = lane & 15;
    int quad = lane >> 4;
    int lb   = w * 256 + l15 * 4 + quad;             // per-lane W slot base
    int b0   = blk >> 5;                             // 0..31
    int c    = blk & 31;

    // ---- scan constants (j = tid) ----
    float bias = lin_b[tid];
    float zscg = fmaxf(sclp[tid], 1e-37f);           // colmax/12, guarded
    float uth  = (1.0f - bias) / zscg;               // spike: u >= uth
    float urst = (0.0f - bias) / zscg;               // reset (v=0)

    // B: both ks halves resident for the whole kernel (8 x dwordx4,
    // L2-hot 64 KB table; latency hides under the encoder phase).
    i32x8 bfr[2][4];
    #pragma unroll
    for (int ks = 0; ks < 2; ++ks)
        #pragma unroll
        for (int nf = 0; nf < 4; ++nf) {
            i32x4 bv = ((const i32x4*)wq4)[(size_t)(ks * 2048 + nf * 64 + lb)];
            bfr[ks][nf][0] = bv[0]; bfr[ks][nf][1] = bv[1];
            bfr[ks][nf][2] = bv[2]; bfr[ks][nf][3] = bv[3];
            bfr[ks][nf][4] = 0; bfr[ks][nf][5] = 0;
            bfr[ks][nf][6] = 0; bfr[ks][nf][7] = 0;
        }

    // ---- BN fold (coeffs pre-halved: folds tau=2) ----
    {
        int h = tid;
        float inv = gamma[h] / sqrtf(var[h] + 1e-5f);
        float K = (conv_b[h] - mean[h]) * inv + beta[h];
        f32x4 cc = {conv_w[h * 3 + 0] * inv * 0.5f,
                    conv_w[h * 3 + 1] * inv * 0.5f,
                    conv_w[h * 3 + 2] * inv * 0.5f, K * 0.5f};
        cfl[h] = cc;
    }
    __syncthreads();                                 // cfl visible

    // ---- encoder: tid<128, packed pair = (b-half 0, b-half 1) ----
    // (verbatim R8 encoder body -- verified absmax 0 there)
    if (tid < 128) {
        int l  = tid;
        int xb = b0 * 4096 + l * 32 + c;
        float xb0 = x[xb],            xb1 = x[xb + 131072];
        float xa0 = (l > 0)   ? x[xb - 32]          : 0.f;
        float xa1 = (l > 0)   ? x[xb + 131072 - 32] : 0.f;
        float xc0 = (l < 127) ? x[xb + 32]          : 0.f;
        float xc1 = (l < 127) ? x[xb + 131072 + 32] : 0.f;
        u32* d0 = bits + l;                          // seq 0 (b-half 0)
        u32* d1 = d0 + 1024;                         // seq 1 (b-half 1)

        f32x2 XA = {xa0, xa1};
        f32x2 XB = {xb0, xb1};
        f32x2 XC = {xc0, xc1};
        const f32x2 hf2 = {0.5f, 0.5f};

        f32x2 v2 = {0.f, 0.f};
        #pragma unroll 1
        for (int hc = 0; hc < 8; ++hc) {
            u32 c0 = 0, c1 = 0;
            #pragma unroll
            for (int k = 0; k < 32; ++k) {
                f32x4 a4 = cfl[hc * 32 + k];
                f32x2 p0 = __builtin_shufflevector(a4, a4, 0, 1); // (w0,w1)
                f32x2 p1 = __builtin_shufflevector(a4, a4, 2, 3); // (w2,K)
                f32x2 e = pk_fma_lw(p1, XC);      // w2*xc + K
                e = pk_fma_b11(p0, XB, e);        // + w1*xb
                e = pk_fma_b00(p0, XA, e);        // + w0*xa
                v2 = pk_fma(hf2, v2, e);          // v = v/2 + e (pre-halved)
                bool s0 = (v2.x >= 1.0f);
                bool s1 = (v2.y >= 1.0f);
                c0 = (c0 << 1) | (u32)s0;
                c1 = (c1 << 1) | (u32)s1;
                v2.x = s0 ? 0.f : v2.x;
                v2.y = s1 ? 0.f : v2.y;
            }
            d0[hc * 128] = __builtin_bitreverse32(c0);  // bit i = spike(hc*32+i)
            d1[hc * 128] = __builtin_bitreverse32(c1);
        }
    }
    __syncthreads();                                 // bits ready, cfl dead

    // ---- phase-fused GEMM + scan, 2 seqs interleaved ----
    float* ZWb = (float*)(smem + 8192 + (size_t)w * 8192); // [2 seq][64][16]
    const u32* bp = bits + quad * 128 + l15;         // + ss*1024+ks*512+mf*16
    int slot = (quad ^ ((l15 >> 1) & 3)) << 2;       // write slot (floats)
    int rkey = (lane >> 1) & 3;                      // read swizzle key

    float uA = urst, uB = urst, sA = 0.f, sB = 0.f;
    i32x8 afr;
    afr[4] = 0; afr[5] = 0; afr[6] = 0; afr[7] = 0;

    #pragma unroll 1
    for (int mf = 0; mf < 8; ++mf) {
        #pragma unroll
        for (int ss = 0; ss < 2; ++ss) {
            f32x4 acc[4];
            #pragma unroll
            for (int nf = 0; nf < 4; ++nf) {
                f32x4 z = {0.f, 0.f, 0.f, 0.f};
                acc[nf] = z;
            }
            #pragma unroll
            for (int ks = 0; ks < 2; ++ks) {
                u32 wb = bp[ss * 1024 + ks * 512 + mf * 16];
                afr[0] = (int)nib_perm(wb & 0xFFu);
                afr[1] = (int)nib_perm((wb >> 8) & 0xFFu);
                afr[2] = (int)nib_perm((wb >> 16) & 0xFFu);
                afr[3] = (int)nib_perm(wb >> 24);
                #pragma unroll
                for (int nf = 0; nf < 4; ++nf) {
                    acc[nf] =
                        __builtin_amdgcn_mfma_scale_f32_16x16x128_f8f6f4(
                            afr, bfr[ks][nf], acc[nf], 4, 4,  // fp4 x fp4
                            0, 0x7F7F7F7F, 0, 0x7F7F7F7F);    // scales 1.0
                }
            }
            float* Z = ZWb + ss * 1024;
            #pragma unroll
            for (int nf = 0; nf < 4; ++nf)           // row = j, 16-t cols
                *(f32x4*)(Z + (nf * 16 + l15) * 16 + slot) = acc[nf];
        }
        // scan this phase's 16 t for both seqs (independent chains)
        #pragma unroll
        for (int g = 0; g < 4; ++g) {
            int go = (g ^ rkey) << 2;
            f32x4 zA = *(const f32x4*)(ZWb + lane * 16 + go);
            f32x4 zB = *(const f32x4*)(ZWb + 1024 + lane * 16 + go);
            #pragma unroll
            for (int r = 0; r < 4; ++r) {
                uA = fmaf(0.5f, uA, zA[r]);
                uB = fmaf(0.5f, uB, zB[r]);
                bool pA = (uA >= uth);
                bool pB = (uB >= uth);
                if (mf == 7 && g == 3 && r == 3) {
                    sA = pA ? 1.f : 0.f;
                    sB = pB ? 1.f : 0.f;
                }
                uA = pA ? urst : uA;
                uB = pB ? urst : uB;
            }
        }
    }

    int n0 = b0 * 32 + c;
    out[(size_t)n0 * 256 + tid]                  = sA;  // (64,1,8192) flat
    out[524288u + (size_t)n0 * 256 + tid]        = sA;  // (64,8192) flat
    int n1 = n0 + 1024;
    out[(size_t)n1 * 256 + tid]                  = sB;
    out[524288u + (size_t)n1 * 256 + tid]        = sB;
}

// ---------------- launcher ----------------
extern "C" void kernel_launch(void* const* d_in, const int* in_sizes, int n_in,
                              void* d_out, int out_size, void* d_ws, size_t ws_size,
                              hipStream_t stream) {
    const float* x      = (const float*)d_in[0];
    const float* conv_w = (const float*)d_in[1];
    const float* conv_b = (const float*)d_in[2];
    const float* gamma  = (const float*)d_in[3];
    const float* beta   = (const float*)d_in[4];
    const float* mean   = (const float*)d_in[5];
    const float* var    = (const float*)d_in[6];
    const float* lin_w  = (const float*)d_in[7];
    const float* lin_b  = (const float*)d_in[8];
    uint8_t* ws = (uint8_t*)d_ws;
    float* out = (float*)d_out;

    hipLaunchKernelGGL(prep_kernel, dim3(256), dim3(256), 0, stream,
                       lin_w, ws);
    hipLaunchKernelGGL(enc_gemm_kernel, dim3(1024), dim3(256), 0, stream,
                       x, conv_w, conv_b, gamma, beta, mean, var,
                       (const uint4*)(ws + OFF_WQ4), lin_b,
                       (const float*)(ws + OFF_SCL), out);
}

// Round 10
// 104.236 us; speedup vs baseline: 1.4430x; 1.0363x over previous
//
#include <hip/hip_runtime.h>
#include <stdint.h>

typedef unsigned short u16;
typedef unsigned int u32;
typedef unsigned long long u64;
typedef unsigned char u8;

typedef __attribute__((ext_vector_type(4))) int   i32x4;
typedef __attribute__((ext_vector_type(8))) int   i32x8;
typedef __attribute__((ext_vector_type(4))) float f32x4;

// ---------------- workspace layout (bytes) ----------------
#define OFF_WQ4  0u                                  // fp4 e2m1 W, fragment order:
// 16B slot = ks*2048 + (j*4 + kblock), ks = k>>7, kblock = (k>>5)&3,
// elem i = k&31 -> byte i>>1, even i = lo nibble (matches A spread order)
#define WQ4_BYTES (2u * 32768u)                      // 64 KiB
#define OFF_SCL  (OFF_WQ4 + WQ4_BYTES)               // float[256]: colmax/12

// ---- 8 bits -> 8 e2m1 nibbles (0x0 / 0x2) via v_perm 2-bit->byte LUT ----
__device__ __forceinline__ u32 nib_perm(u32 byte) {
    u32 t1 = byte | (byte << 6);
    u32 t2 = t1 | (t1 << 12);
    u32 sel = t2 & 0x03030303u;
    // LUT bytes: idx0->0x00 idx1->0x02 idx2->0x20 idx3->0x22
    return __builtin_amdgcn_perm(0x22200200u, 0x22200200u, sel);
}

// ---------------- kernel 1: W prep (256 blocks) ----------------
__global__ __launch_bounds__(256) void prep_kernel(
    const float* __restrict__ lin_w, uint8_t* __restrict__ ws) {
    __shared__ float red[256];
    __shared__ u8 nib[256];
    int j = blockIdx.x, k = threadIdx.x;
    float wv = lin_w[j * 256 + k];
    red[k] = fabsf(wv);
    __syncthreads();
    #pragma unroll
    for (int s = 128; s > 0; s >>= 1) {
        if (k < s) red[k] = fmaxf(red[k], red[k + s]);
        __syncthreads();
    }
    float m = red[0];
    float S = (m > 0.f) ? 6.0f / m : 0.f;
    float v6 = wv * S;
    float av = fabsf(v6);
    int code;
    if      (av < 0.25f) code = 0;
    else if (av < 0.75f) code = 1;
    else if (av < 1.25f) code = 2;
    else if (av < 1.75f) code = 3;
    else if (av < 2.5f)  code = 4;
    else if (av < 3.5f)  code = 5;
    else if (av < 5.0f)  code = 6;
    else                 code = 7;
    nib[k] = (u8)(((v6 < 0.f && code) ? 8 : 0) | code);
    __syncthreads();
    if (k < 128) {
        u8 byte = (u8)(nib[2 * k] | (nib[2 * k + 1] << 4));
        int ks = k >> 6, kb = (k >> 4) & 3, bi = k & 15;
        (ws + OFF_WQ4)[ks * 32768 + (j * 4 + kb) * 16 + bi] = byte;
    }
    if (k == 0) ((float*)(ws + OFF_SCL))[j] = m * (1.0f / 12.0f);
}

// ---------------- kernel 2: FUSED encoder + pipelined GEMM + scan ------
// 1024 blocks x 256 threads, __launch_bounds__(256,3), 3 blocks/CU.
// Block = (b0,c), 2 sequences (b-halves).
// R10 changes vs R9 (both target the measured 60%-idle main phase):
//  (a) ALL 256 threads encode (scalar chain each, thread=(bh,l)): 2x the
//      active waves in the encoder phase (R9: only tid<128 worked).
//  (b) phase-pipelined scan: prev phase's z held in regs (pz, 32 VGPR).
//      Per mf: {spread+MFMA+ds_write mf} -> {scan pz = mf-1} ->
//      {ds_read mf -> pz}. The LDS round trip leaves the critical path:
//      write-drain hides under scan VALU, read latency under next phase's
//      spread+MFMA. Scan order over t unchanged -> bit-identical.
// LDS = 8192 bits + 4 waves x 8192 ZW = 40960.
#define COMPUTE_WRITE(MF)                                                  \
    _Pragma("unroll") for (int ss = 0; ss < 2; ++ss) {                     \
        f32x4 acc[4];                                                      \
        _Pragma("unroll") for (int nf = 0; nf < 4; ++nf) {                 \
            f32x4 z = {0.f, 0.f, 0.f, 0.f};                                \
            acc[nf] = z;                                                   \
        }                                                                  \
        _Pragma("unroll") for (int ks = 0; ks < 2; ++ks) {                 \
            u32 wb = bp[ss * 1024 + ks * 512 + (MF) * 16];                 \
            afr[0] = (int)nib_perm(wb & 0xFFu);                            \
            afr[1] = (int)nib_perm((wb >> 8) & 0xFFu);                     \
            afr[2] = (int)nib_perm((wb >> 16) & 0xFFu);                    \
            afr[3] = (int)nib_perm(wb >> 24);                              \
            _Pragma("unroll") for (int nf = 0; nf < 4; ++nf)               \
                acc[nf] = __builtin_amdgcn_mfma_scale_f32_16x16x128_f8f6f4(\
                    afr, bfr[ks][nf], acc[nf], 4, 4,                       \
                    0, 0x7F7F7F7F, 0, 0x7F7F7F7F);                         \
        }                                                                  \
        float* Z = ZWb + ss * 1024;                                        \
        _Pragma("unroll") for (int nf = 0; nf < 4; ++nf)                   \
            *(f32x4*)(Z + (nf * 16 + l15) * 16 + slot) = acc[nf];          \
    }

#define READ_PZ()                                                          \
    _Pragma("unroll") for (int g = 0; g < 4; ++g) {                        \
        int go = (g ^ rkey) << 2;                                          \
        pz[0][g] = *(const f32x4*)(ZWb + lane * 16 + go);                  \
        pz[1][g] = *(const f32x4*)(ZWb + 1024 + lane * 16 + go);           \
    }

#define SCAN_PZ(LAST)                                                      \
    _Pragma("unroll") for (int g = 0; g < 4; ++g) {                        \
        _Pragma("unroll") for (int r = 0; r < 4; ++r) {                    \
            uA = fmaf(0.5f, uA, pz[0][g][r]);                              \
            uB = fmaf(0.5f, uB, pz[1][g][r]);                              \
            bool pA = (uA >= uth);                                         \
            bool pB = (uB >= uth);                                         \
            if ((LAST) && g == 3 && r == 3) {                              \
                sA = pA ? 1.f : 0.f;                                       \
                sB = pB ? 1.f : 0.f;                                       \
            }                                                              \
            uA = pA ? urst : uA;                                           \
            uB = pB ? urst : uB;                                           \
        }                                                                  \
    }

__global__ __launch_bounds__(256, 3) void enc_gemm_kernel(
    const float* __restrict__ x,
    const float* __restrict__ conv_w, const float* __restrict__ conv_b,
    const float* __restrict__ gamma,  const float* __restrict__ beta,
    const float* __restrict__ mean,   const float* __restrict__ var,
    const uint4* __restrict__ wq4,
    const float* __restrict__ lin_b,  const float* __restrict__ sclp,
    float* __restrict__ out) {
    __shared__ __align__(16) uint8_t smem[40960];
    u32*   bits = (u32*)smem;                        // [2 bh][8 hc][128 l]
    f32x4* cfl  = (f32x4*)(smem + 8192);             // overlay on ZW region

    int tid  = threadIdx.x;
    int blk  = blockIdx.x;                           // 0..1023
    int lane = tid & 63;
    int w    = tid >> 6;
    int l15  = lane & 15;
    int quad = lane >> 4;
    int lb   = w * 256 + l15 * 4 + quad;             // per-lane W slot base
    int b0   = blk >> 5;                             // 0..31
    int c    = blk & 31;

    // ---- scan constants (j = tid) ----
    float bias = lin_b[tid];
    float zscg = fmaxf(sclp[tid], 1e-37f);           // colmax/12, guarded
    float uth  = (1.0f - bias) / zscg;               // spike: u >= uth
    float urst = (0.0f - bias) / zscg;               // reset (v=0)

    // B: both ks halves resident for the whole kernel (8 x dwordx4,
    // L2-hot 64 KB table; latency hides under the encoder phase).
    i32x8 bfr[2][4];
    #pragma unroll
    for (int ks = 0; ks < 2; ++ks)
        #pragma unroll
        for (int nf = 0; nf < 4; ++nf) {
            i32x4 bv = ((const i32x4*)wq4)[(size_t)(ks * 2048 + nf * 64 + lb)];
            bfr[ks][nf][0] = bv[0]; bfr[ks][nf][1] = bv[1];
            bfr[ks][nf][2] = bv[2]; bfr[ks][nf][3] = bv[3];
            bfr[ks][nf][4] = 0; bfr[ks][nf][5] = 0;
            bfr[ks][nf][6] = 0; bfr[ks][nf][7] = 0;
        }

    // ---- BN fold (coeffs pre-halved: folds tau=2) ----
    {
        int h = tid;
        float inv = gamma[h] / sqrtf(var[h] + 1e-5f);
        float K = (conv_b[h] - mean[h]) * inv + beta[h];
        f32x4 cc = {conv_w[h * 3 + 0] * inv * 0.5f,
                    conv_w[h * 3 + 1] * inv * 0.5f,
                    conv_w[h * 3 + 2] * inv * 0.5f, K * 0.5f};
        cfl[h] = cc;
    }
    __syncthreads();                                 // cfl visible

    // ---- encoder: ALL 256 threads, scalar chain, thread = (bh, l) ----
    // (R7's verified scalar body, re-indexed to this block's fixed c)
    {
        int l  = tid & 127;
        int bh = tid >> 7;
        int xb = b0 * 4096 + l * 32 + c + bh * 131072;
        float xbv = x[xb];
        float xav = (l > 0)   ? x[xb - 32] : 0.f;
        float xcv = (l < 127) ? x[xb + 32] : 0.f;
        u32* dst = bits + bh * 1024 + l;             // seq = bh
        float v = 0.f;
        #pragma unroll 1
        for (int hc = 0; hc < 8; ++hc) {
            u32 cc = 0;
            #pragma unroll
            for (int k = 0; k < 32; ++k) {
                f32x4 a4 = cfl[hc * 32 + k];
                float e = fmaf(a4[2], xcv, a4[3]);
                e = fmaf(a4[1], xbv, e);
                e = fmaf(a4[0], xav, e);
                v = fmaf(0.5f, v, e);                // v = v/2 + e (pre-halved)
                bool sp = (v >= 1.0f);
                cc = (cc << 1) | (u32)sp;
                v = sp ? 0.f : v;
            }
            dst[hc * 128] = __builtin_bitreverse32(cc); // bit i = spike(hc*32+i)
        }
    }
    __syncthreads();                                 // bits ready, cfl dead

    // ---- pipelined GEMM + scan, 2 seqs interleaved ----
    float* ZWb = (float*)(smem + 8192 + (size_t)w * 8192); // [2 seq][64][16]
    const u32* bp = bits + quad * 128 + l15;         // + ss*1024+ks*512+mf*16
    int slot = (quad ^ ((l15 >> 1) & 3)) << 2;       // write slot (floats)
    int rkey = (lane >> 1) & 3;                      // read swizzle key

    float uA = urst, uB = urst, sA = 0.f, sB = 0.f;
    f32x4 pz[2][4];                                  // prev-phase z regs
    i32x8 afr;
    afr[4] = 0; afr[5] = 0; afr[6] = 0; afr[7] = 0;

    COMPUTE_WRITE(0)                                 // prologue: phase 0
    READ_PZ()
    #pragma unroll 1
    for (int mf = 1; mf < 8; ++mf) {
        COMPUTE_WRITE(mf)                            // spread+MFMA+write mf
        SCAN_PZ(false)                               // scan phase mf-1 (regs)
        READ_PZ()                                    // load mf -> pz
    }
    SCAN_PZ(true)                                    // epilogue: phase 7

    int n0 = b0 * 32 + c;
    out[(size_t)n0 * 256 + tid]           = sA;      // (64,1,8192) flat
    out[524288u + (size_t)n0 * 256 + tid] = sA;      // (64,8192) flat
    int n1 = n0 + 1024;
    out[(size_t)n1 * 256 + tid]           = sB;
    out[524288u + (size_t)n1 * 256 + tid] = sB;
}

// ---------------- launcher ----------------
extern "C" void kernel_launch(void* const* d_in, const int* in_sizes, int n_in,
                              void* d_out, int out_size, void* d_ws, size_t ws_size,
                              hipStream_t stream) {
    const float* x      = (const float*)d_in[0];
    const float* conv_w = (const float*)d_in[1];
    const float* conv_b = (const float*)d_in[2];
    const float* gamma  = (const float*)d_in[3];
    const float* beta   = (const float*)d_in[4];
    const float* mean   = (const float*)d_in[5];
    const float* var    = (const float*)d_in[6];
    const float* lin_w  = (const float*)d_in[7];
    const float* lin_b  = (const float*)d_in[8];
    uint8_t* ws = (uint8_t*)d_ws;
    float* out = (float*)d_out;

    hipLaunchKernelGGL(prep_kernel, dim3(256), dim3(256), 0, stream,
                       lin_w, ws);
    hipLaunchKernelGGL(enc_gemm_kernel, dim3(1024), dim3(256), 0, stream,
                       x, conv_w, conv_b, gamma, beta, mean, var,
                       (const uint4*)(ws + OFF_WQ4), lin_b,
                       (const float*)(ws + OFF_SCL), out);
}